// Round 2
// baseline (2209.676 us; speedup 1.0000x reference)
//
#include <hip/hip_runtime.h>
#include <hip/hip_cooperative_groups.h>
#include <math.h>

namespace cg = cooperative_groups;

#define BB 8
#define TT 16
#define SS 400
#define HH 512
#define EE 128
#define VV 50000
#define VE 50050
#define OOVn 50

// output offsets (floats)
#define O1 6406400
#define O2 6410496
#define O3 6414592
#define O4 6418688
#define O5 6469888
#define O6 6469896

typedef __attribute__((ext_vector_type(4))) float floatx4;
typedef __attribute__((ext_vector_type(8))) short short8;

__device__ __forceinline__ float sigm(float x){ return 1.0f/(1.0f+__expf(-x)); }

__device__ __forceinline__ unsigned short f2bf(float f){
  union { float f; unsigned int u; } v; v.f = f;
  unsigned int u = v.u;
  return (unsigned short)((u + 0x7FFFu + ((u >> 16) & 1u)) >> 16);
}

// ---------------------------------------------------------------------------
// GEMM: C[M,N] = A[M,K] @ B[N,K]^T (+bias). fp32 in, bf16 MFMA, fp32 out.
// Tile 128(M) x 64(N). M multiple of 128, K multiple of 64, N ragged-guarded.
// Register-batched staging: all 12 float4 global loads issued before any use.
// permute: C row for logical row m is (m&7)*16 + (m>>3)  (m = t*8+b -> b*16+t)
// ---------------------------------------------------------------------------
__global__ __launch_bounds__(256)
void gemm_bt(const float* __restrict__ A, int lda,
             const float* __restrict__ Bm, int ldb,
             const float* __restrict__ bias,
             float* __restrict__ Cm, int ldc,
             int N, int K, int permute)
{
  __shared__ unsigned short Ash[128*72];
  __shared__ unsigned short Bsh[64*72];
  int tid = threadIdx.x;
  int mbase = blockIdx.x * 128;
  int nbase = blockIdx.y * 64;
  int wave = tid >> 6, lane = tid & 63;
  int wm = (wave & 1) * 64, wn = (wave >> 1) * 32;
  int fl = lane & 15, quad = lane >> 4;

  floatx4 acc[4][2];
  for (int i=0;i<4;i++) for(int j=0;j<2;j++) acc[i][j] = (floatx4)(0.0f);

  for (int kc = 0; kc < K; kc += 64) {
    float4 ra[8], rb[4];
#pragma unroll
    for (int i = 0; i < 8; ++i) {
      int idx = tid + i*256;
      int row = idx >> 4;
      int c4 = (idx & 15) << 2;
      ra[i] = *(const float4*)(A + (size_t)(mbase+row)*lda + kc + c4);
    }
#pragma unroll
    for (int i = 0; i < 4; ++i) {
      int idx = tid + i*256;
      int row = idx >> 4;
      int c4 = (idx & 15) << 2;
      int gn = nbase + row;
      if (gn < N) rb[i] = *(const float4*)(Bm + (size_t)gn*ldb + kc + c4);
      else { rb[i].x = 0.f; rb[i].y = 0.f; rb[i].z = 0.f; rb[i].w = 0.f; }
    }
    __syncthreads();   // prev chunk's frag reads done; staging loads in flight
#pragma unroll
    for (int i = 0; i < 8; ++i) {
      int idx = tid + i*256;
      int o = (idx >> 4)*72 + ((idx & 15) << 2);
      Ash[o+0]=f2bf(ra[i].x); Ash[o+1]=f2bf(ra[i].y); Ash[o+2]=f2bf(ra[i].z); Ash[o+3]=f2bf(ra[i].w);
    }
#pragma unroll
    for (int i = 0; i < 4; ++i) {
      int idx = tid + i*256;
      int o = (idx >> 4)*72 + ((idx & 15) << 2);
      Bsh[o+0]=f2bf(rb[i].x); Bsh[o+1]=f2bf(rb[i].y); Bsh[o+2]=f2bf(rb[i].z); Bsh[o+3]=f2bf(rb[i].w);
    }
    __syncthreads();
#pragma unroll
    for (int ks = 0; ks < 2; ++ks) {
      short8 af[4], bfr[2];
      int ko = ks*32 + quad*8;
#pragma unroll
      for (int i=0;i<4;i++) af[i]  = *(const short8*)&Ash[(wm + i*16 + fl)*72 + ko];
#pragma unroll
      for (int j=0;j<2;j++) bfr[j] = *(const short8*)&Bsh[(wn + j*16 + fl)*72 + ko];
#pragma unroll
      for (int i=0;i<4;i++)
#pragma unroll
        for (int j=0;j<2;j++)
          acc[i][j] = __builtin_amdgcn_mfma_f32_16x16x32_bf16(af[i], bfr[j], acc[i][j], 0,0,0);
    }
    __syncthreads();
  }
  for (int i=0;i<4;i++){
    for (int j=0;j<2;j++){
      int nc = nbase + wn + j*16 + fl;
      if (nc >= N) continue;
      float bv = bias ? bias[nc] : 0.0f;
      for (int r=0;r<4;r++){
        int mg = mbase + wm + i*16 + quad*4 + r;
        int orow = permute ? ((mg & 7)*16 + (mg >> 3)) : mg;
        Cm[(size_t)orow*ldc + nc] = acc[i][j][r] + bv;
      }
    }
  }
}

// ---------------------------------------------------------------------------
// Cooperative recurrence kernel: all 16 LSTM+attention steps, 1 dispatch.
// Grid 128 blocks x 512 threads, 5 grid syncs per step.
// ---------------------------------------------------------------------------
struct CoopArgs {
  const float *emb, *context, *h0, *c0, *enc, *masks, *coverage;
  const float *wih, *whh, *bih, *bhh, *covw, *ew, *eb, *vvec, *xw, *xb, *pw, *pb;
  const float *encp;
  float *A1, *xall, *h_cur, *c_cur, *gatesH, *hp, *evec, *pgen, *out;
};

// gatesH[r,b] = b_ih[r]+b_hh[r] + h[b]@W_hh[r,:]  for r in [blk*32, +32)
__device__ __forceinline__ void gatesH_phase(const CoopArgs& a, float* sm, int blk, int tid,
                                             const float* hsrc)
{
  int r0 = blk * 32;
  int rr = tid >> 4, b = (tid >> 1) & 7, kh = tid & 1;
  const float* w  = a.whh + (size_t)(r0+rr)*512 + kh*256;
  const float* hh = hsrc + b*512 + kh*256;
  float acc = 0.f;
  for (int k = 0; k < 256; k += 4) {
    float4 w4 = *(const float4*)(w + k);
    float4 h4 = *(const float4*)(hh + k);
    acc += w4.x*h4.x + w4.y*h4.y + w4.z*h4.z + w4.w*h4.w;
  }
  sm[tid] = acc;
  __syncthreads();
  if (tid < 256) {
    int rr2 = tid >> 3, b2 = tid & 7;
    int r = r0 + rr2;
    a.gatesH[(size_t)r*8 + b2] = a.bih[r] + a.bhh[r] + sm[rr2*16 + b2*2] + sm[rr2*16 + b2*2 + 1];
  }
}

__global__ __launch_bounds__(512, 1) void coop_loop(CoopArgs a)
{
  cg::grid_group grid = cg::this_grid();
  __shared__ float sm[5120];   // 20 KB, aliased per phase
  const int blk = blockIdx.x, tid = threadIdx.x;

  // ---- Prologue: gatesH(0) from h0 ----
  if (blk < 64) gatesH_phase(a, sm, blk, tid, a.h0);
  grid.sync();

  for (int t = 0; t < TT; ++t) {
    // ---- PH1: x(t) = [emb_t ; ctx_{t-1}] @ xw^T + xb ; blocks 0..63 ----
    if (blk < 64) {
      int b = blk >> 3, es = blk & 7;
      float* in   = sm;        // 640
      float* part = sm + 640;  // 512
      const float* ctxp = (t==0) ? a.context + b*512
                                 : a.A1 + ((size_t)((t-1)*8+b))*1024 + 512;
      for (int i = tid; i < 640; i += 512)
        in[i] = (i < 128) ? a.emb[(size_t)(b*TT+t)*EE + i] : ctxp[i-128];
      __syncthreads();
      int el = tid >> 5;            // 0..15
      int kq = tid & 31;            // 0..31, 20-wide k segments
      int e  = es*16 + el;
      const float* w  = a.xw + (size_t)e*640 + kq*20;
      const float* ip = in + kq*20;
      float acc = 0.f;
      for (int k = 0; k < 20; ++k) acc += w[k]*ip[k];
      part[el*32 + kq] = acc;
      __syncthreads();
      if (tid < 16) {
        float s2 = a.xb[es*16 + tid];
        for (int q = 0; q < 32; ++q) s2 += part[tid*32 + q];
        a.xall[(size_t)(t*8+b)*EE + es*16 + tid] = s2;
      }
    }
    grid.sync();

    // ---- PH2: gates = gatesH + x@W_ih^T -> LSTM cell ; blocks 0..63 ----
    if (blk < 64) {
      int b = blk >> 3, js = blk & 7;
      float* xsh   = sm;        // 128
      float* gpart = sm + 128;  // 512
      float* gall  = sm + 640;  // 256
      for (int i = tid; i < 128; i += 512) xsh[i] = a.xall[(size_t)(t*8+b)*EE + i];
      __syncthreads();
      {
        int dotid = tid >> 1, kh = tid & 1;
        int jj = dotid & 63, g = dotid >> 6;
        int r = g*512 + js*64 + jj;
        const float* w  = a.wih + (size_t)r*128 + kh*64;
        const float* xp = xsh + kh*64;
        float acc = 0.f;
        for (int k = 0; k < 64; k += 4) {
          float4 w4 = *(const float4*)(w + k);
          acc += w4.x*xp[k] + w4.y*xp[k+1] + w4.z*xp[k+2] + w4.w*xp[k+3];
        }
        gpart[tid] = acc;
      }
      __syncthreads();
      if (tid < 256) {
        int jj = tid & 63, g = tid >> 6;
        int r = g*512 + js*64 + jj;
        gall[tid] = gpart[tid*2] + gpart[tid*2+1] + a.gatesH[(size_t)r*8 + b];
      }
      __syncthreads();
      if (tid < 64) {
        int j = js*64 + tid;
        float gi = gall[tid], gf = gall[64+tid], gg = gall[128+tid], go = gall[192+tid];
        float cp = (t==0) ? a.c0[b*512+j] : a.c_cur[b*512+j];
        float cn = sigm(gf)*cp + sigm(gi)*tanhf(gg);
        float hn = sigm(go)*tanhf(cn);
        a.c_cur[b*512+j] = cn;
        a.h_cur[b*512+j] = hn;
        a.A1[((size_t)(t*8+b))*1024 + j] = hn;
      }
    }
    grid.sync();

    // ---- PH3: hp(t) (blocks 64..127)  ||  gatesH(t+1) (blocks 0..63) ----
    if (blk < 64) {
      if (t < TT-1) gatesH_phase(a, sm, blk, tid, a.h_cur);
    } else {
      int k2 = blk - 64, b = k2 >> 3, ps = k2 & 7;
      float* part = sm;   // 512
      int pp = tid >> 3, k8 = tid & 7;
      int p = ps*64 + pp;
      const float* w  = a.ew + (size_t)p*1024 + k8*64;
      const float* hh = a.h_cur + b*512 + k8*64;
      float acc = 0.f;
      for (int k = 0; k < 64; k += 4) {
        float4 w4 = *(const float4*)(w + k);
        float4 h4 = *(const float4*)(hh + k);
        acc += w4.x*h4.x + w4.y*h4.y + w4.z*h4.z + w4.w*h4.w;
      }
      part[tid] = acc;
      __syncthreads();
      if (tid < 64) {
        int p2 = ps*64 + tid;
        float s2 = a.eb[p2];
        for (int q = 0; q < 8; ++q) s2 += part[tid*8 + q];
        a.hp[b*512 + p2] = s2;
      }
    }
    grid.sync();

    // ---- PH4: e[b,s] = sum_h tanh(hp + encp + cov*covw) * v ; all 128 ----
    {
      int b = blk >> 4, ss = blk & 15;
      float* hpl = sm;          // 512
      float* vl  = sm + 512;
      float* cwl = sm + 1024;
      for (int i = tid; i < 512; i += 512) {
        hpl[i] = a.hp[b*512+i]; vl[i] = a.vvec[i]; cwl[i] = a.covw[i];
      }
      __syncthreads();
      int w = tid >> 6, lane = tid & 63;
      const float* covp = (t==0) ? a.coverage + b*SS
                                 : a.out + O6 + ((size_t)(b*TT + t-1))*SS;
      for (int q = 0; q < 4; ++q) {
        int sl = w + q*8;
        if (sl < 25) {
          int s = ss*25 + sl;
          float cv = covp[s];
          const float* ep = a.encp + ((size_t)(b*SS+s))*512;
          float acc = 0.f;
          for (int u = 0; u < 8; ++u) {
            int h = lane + u*64;                     // bank-friendly stride
            acc += tanhf(hpl[h] + ep[h] + cv*cwl[h]) * vl[h];
          }
          for (int off = 32; off > 0; off >>= 1) acc += __shfl_down(acc, off);
          if (lane == 0) a.evec[b*SS + s] = acc;
        }
      }
    }
    grid.sync();

    // ---- PH5: softmax(+mask renorm) + coverage + ctx ; all 128 blocks ----
    {
      int b = blk >> 4, part_ = blk & 15;
      float* evl   = sm;         // 400
      float* prl   = sm + 400;   // 400
      float* red   = sm + 800;   // 26
      float* cpart = sm + 832;   // 512
      for (int i = tid; i < 400; i += 512) evl[i] = a.evec[b*SS + i];
      __syncthreads();
      int w = tid >> 6, lane = tid & 63;
      float ev = (tid < 400) ? evl[tid] : -1e30f;
      float mx = ev;
      for (int off = 32; off > 0; off >>= 1) mx = fmaxf(mx, __shfl_down(mx, off));
      if (lane == 0) red[w] = mx;
      __syncthreads();
      if (tid == 0) { float m2 = red[0]; for (int i2=1;i2<8;i2++) m2 = fmaxf(m2, red[i2]); red[8] = m2; }
      __syncthreads();
      float smx = red[8];
      float p1 = (tid < 400) ? __expf(ev - smx) : 0.f;
      float mk = (tid < 400) ? a.masks[b*SS + tid] : 0.f;
      float pm = p1*mk;
      float s1 = p1, s2 = pm;
      for (int off = 32; off > 0; off >>= 1) { s1 += __shfl_down(s1,off); s2 += __shfl_down(s2,off); }
      if (lane == 0) { red[9 + w] = s1; red[17 + w] = s2; }
      __syncthreads();
      if (tid == 0) {
        float d1=0.f, d2=0.f;
        for (int i2=0;i2<8;i2++){ d1 += red[9+i2]; d2 += red[17+i2]; }
        red[25] = d2 + 1e-12f*d1;
      }
      __syncthreads();
      float denom = red[25];
      if (tid < 400) prl[tid] = pm / denom;
      __syncthreads();
      const float* covp = (t==0) ? a.coverage + b*SS
                                 : a.out + O6 + ((size_t)(b*TT + t-1))*SS;
      if (part_ == 0 && tid < 400) {
        size_t o = ((size_t)(b*TT + t))*SS + tid;
        a.out[O4 + o] = prl[tid];
        a.out[O6 + o] = covp[tid] + prl[tid];
      }
      {
        int c = (tid & 31), sg = tid >> 5;   // 16 s-groups of 25
        const float* ep = a.enc + ((size_t)(b*SS + sg*25))*512 + part_*32 + c;
        float acc = 0.f;
        for (int s3 = 0; s3 < 25; ++s3) acc += prl[sg*25 + s3] * ep[(size_t)s3*512];
        cpart[sg*32 + c] = acc;
      }
      __syncthreads();
      if (tid < 32) {
        float sc = 0.f;
        for (int q = 0; q < 16; ++q) sc += cpart[q*32 + tid];
        a.A1[((size_t)(t*8+b))*1024 + 512 + part_*32 + tid] = sc;
      }
    }
    grid.sync();
  }

  // ---- Epilogue: pgen (all t), out1/2/3, out5 ----
  if (blk == 0) {
    float* part = sm;
    int m = tid >> 2, q = tid & 3;
    const float* hr = a.A1 + (size_t)m*1024;   // [h | ctx]
    const float* xr = a.xall + (size_t)m*EE;
    float acc = 0.f;
    int k0 = q*288, k1 = k0 + 288;
    for (int k = k0; k < k1; ++k) {
      float in_;
      if (k < 512)       in_ = hr[512 + k];    // ctx
      else if (k < 1024) in_ = hr[k - 512];    // h
      else               in_ = xr[k - 1024];   // x
      acc += a.pw[k] * in_;
    }
    part[tid] = acc;
    __syncthreads();
    if (tid < 128) {
      float s2 = part[tid*4] + part[tid*4+1] + part[tid*4+2] + part[tid*4+3] + a.pb[0];
      float pg = sigm(s2);
      a.pgen[tid] = pg;
      if ((tid >> 3) == 15) a.out[O5 + (tid & 7)] = pg;
    }
  } else if (blk == 1) {
    for (int i = tid; i < 4096; i += 512) {
      int b = i >> 9, j = i & 511;
      a.out[O1 + i] = a.A1[((size_t)(15*8+b))*1024 + 512 + j];
    }
  } else if (blk == 2) {
    for (int i = tid; i < 4096; i += 512) a.out[O2 + i] = a.h_cur[i];
  } else if (blk == 3) {
    for (int i = tid; i < 4096; i += 512) a.out[O3 + i] = a.c_cur[i];
  }
}

// ---------------------------------------------------------------------------
// in-place vocab softmax + p_gen scale + OOV cols + copy-mechanism scatter
// ---------------------------------------------------------------------------
__global__ __launch_bounds__(256) void k_final(
  float* __restrict__ out, const float* __restrict__ pgen,
  const float* __restrict__ ez, const int* __restrict__ extidx)
{
  int m = blockIdx.x;           // m = t*8+b
  int b = m & 7, t = m >> 3;
  float* row = out + ((size_t)(b*TT + t))*VE;
  int tid = threadIdx.x;
  __shared__ float red[4];
  __shared__ float smx, ssum;
  float mx = -1e30f;
  for (int v2 = tid; v2 < VV; v2 += 256) mx = fmaxf(mx, row[v2]);
  for (int off=32; off>0; off>>=1) mx = fmaxf(mx, __shfl_down(mx, off));
  int wave = tid>>6, lane = tid&63;
  if (lane==0) red[wave] = mx;
  __syncthreads();
  if (tid==0){ float m2=red[0]; for(int i=1;i<4;i++) m2=fmaxf(m2,red[i]); smx=m2; }
  __syncthreads();
  float mxv = smx;
  float sm = 0.0f;
  for (int v2 = tid; v2 < VV; v2 += 256) {
    float e2 = __expf(row[v2] - mxv);
    row[v2] = e2;
    sm += e2;
  }
  for (int off=32; off>0; off>>=1) sm += __shfl_down(sm, off);
  if (lane==0) red[wave] = sm;
  __syncthreads();
  if (tid==0){ float s2=0; for(int i=0;i<4;i++) s2+=red[i]; ssum=s2; }
  __syncthreads();
  float pg = pgen[m];
  float scale = pg / ssum;
  for (int v2 = tid; v2 < VV; v2 += 256) row[v2] *= scale;
  for (int v2 = VV + tid; v2 < VE; v2 += 256) row[v2] = ez[b*OOVn + (v2-VV)];
  __syncthreads();
  float onem = 1.0f - pg;
  const float* pr = out + O4 + ((size_t)(b*TT+t))*SS;
  for (int s2 = tid; s2 < SS; s2 += 256) {
    int ix = extidx[b*SS + s2];
    atomicAdd(&row[ix], onem * pr[s2]);
  }
}

extern "C" void kernel_launch(void* const* d_in, const int* in_sizes, int n_in,
                              void* d_out, int out_size, void* d_ws, size_t ws_size,
                              hipStream_t stream)
{
  (void)in_sizes; (void)n_in; (void)out_size; (void)ws_size;
  const float* emb      = (const float*)d_in[0];
  const float* context  = (const float*)d_in[1];
  const float* h0       = (const float*)d_in[2];
  const float* c0       = (const float*)d_in[3];
  const float* enc      = (const float*)d_in[4];
  const float* masks    = (const float*)d_in[5];
  const float* ez       = (const float*)d_in[6];
  const int*   extidx   = (const int*)d_in[7];
  const float* coverage = (const float*)d_in[8];
  const float* wih      = (const float*)d_in[9];
  const float* whh      = (const float*)d_in[10];
  const float* bih      = (const float*)d_in[11];
  const float* bhh      = (const float*)d_in[12];
  const float* covw     = (const float*)d_in[13];
  const float* ew       = (const float*)d_in[14];
  const float* eb       = (const float*)d_in[15];
  const float* vvec     = (const float*)d_in[16];
  const float* xw       = (const float*)d_in[17];
  const float* xb       = (const float*)d_in[18];
  const float* aw       = (const float*)d_in[19];
  const float* ab       = (const float*)d_in[20];
  const float* vw       = (const float*)d_in[21];
  const float* vb       = (const float*)d_in[22];
  const float* pw       = (const float*)d_in[23];
  const float* pb       = (const float*)d_in[24];
  float* out = (float*)d_out;

  float* ws = (float*)d_ws;
  float* A1         = ws;                    // 128 x 1024 : [h | ctx] per (t,b)
  float* xall       = A1 + 131072;           // 128 x 128
  float* h_cur      = xall + 16384;          // 8 x 512
  float* c_cur      = h_cur + 4096;          // 8 x 512
  float* gatesH     = c_cur + 4096;          // 2048 x 8
  float* hp         = gatesH + 16384;        // 8 x 512
  float* evec       = hp + 4096;             // 8 x 400
  float* attnd_feat = evec + 3200;           // 128 x 512
  float* pgen       = attnd_feat + 65536;    // 128
  float* enc_proj   = out;                   // 3200 x 512, borrows out0 region

  // enc_proj = enc @ energy_w[:,512:].T   (time-invariant attention part)
  gemm_bt<<<dim3(25,8), 256, 0, stream>>>(enc, 512, ew + 512, 1024,
                                          (const float*)nullptr, enc_proj, 512, 512, 512, 0);

  CoopArgs ca;
  ca.emb = emb; ca.context = context; ca.h0 = h0; ca.c0 = c0; ca.enc = enc;
  ca.masks = masks; ca.coverage = coverage;
  ca.wih = wih; ca.whh = whh; ca.bih = bih; ca.bhh = bhh; ca.covw = covw;
  ca.ew = ew; ca.eb = eb; ca.vvec = vvec; ca.xw = xw; ca.xb = xb;
  ca.pw = pw; ca.pb = pb; ca.encp = enc_proj;
  ca.A1 = A1; ca.xall = xall; ca.h_cur = h_cur; ca.c_cur = c_cur;
  ca.gatesH = gatesH; ca.hp = hp; ca.evec = evec; ca.pgen = pgen; ca.out = out;

  void* cargs[] = { &ca };
  hipLaunchCooperativeKernel((const void*)coop_loop, dim3(128), dim3(512),
                             cargs, 0, stream);

  // attnd_feat = [h|ctx] @ attnd_w.T + attnd_b
  gemm_bt<<<dim3(1,8), 256, 0, stream>>>(A1, 1024, aw, 1024, ab, attnd_feat, 512, 512, 1024, 0);
  // logits (all 16 steps batched) = attnd_feat @ vocab_w.T + vocab_b -> out rows (b*16+t)
  gemm_bt<<<dim3(1,782), 256, 0, stream>>>(attnd_feat, 512, vw, 512, vb, out, VE, VV, 512, 1);
  k_final<<<128, 256, 0, stream>>>(out, pgen, ez, extidx);
}

// Round 3
// 997.477 us; speedup vs baseline: 2.2153x; 2.2153x over previous
//
#include <hip/hip_runtime.h>
#include <math.h>

#define BB 8
#define TT 16
#define SS 400
#define HH 512
#define EE 128
#define VV 50000
#define VE 50050
#define OOVn 50

// output offsets (floats)
#define O1 6406400
#define O2 6410496
#define O3 6414592
#define O4 6418688
#define O5 6469888
#define O6 6469896

// scratch inside out0 region (float offsets; region free until logits GEMM)
#define G_OFF    0          // 2048x1152 ushort = 1,179,648 floats
#define ENCB_OFF 1200000    // 3200x512 ushort  =   819,200 floats
#define EWHB_OFF 2100000    // 512x512 ushort   =   131,072 floats
#define ENCP_OFF 2300000    // 3200x512 ushort  =   819,200 floats

typedef __attribute__((ext_vector_type(4))) float floatx4;
typedef __attribute__((ext_vector_type(8))) short short8;
typedef __attribute__((ext_vector_type(8))) unsigned short ushort8_t;
typedef __attribute__((ext_vector_type(4))) unsigned short ushort4_t;

__device__ __forceinline__ float sigm(float x){ return 1.0f/(1.0f+__expf(-x)); }

__device__ __forceinline__ unsigned short f2bf(float f){
  union { float f; unsigned int u; } v; v.f = f;
  unsigned int u = v.u;
  return (unsigned short)((u + 0x7FFFu + ((u >> 16) & 1u)) >> 16);
}
__device__ __forceinline__ float bfu(unsigned short u){
  union { unsigned int i; float f; } v; v.i = ((unsigned int)u) << 16; return v.f;
}

// ---------------------------------------------------------------------------
// GEMM: C[M,N] = A[M,K] @ B[N,K]^T (+bias). fp32 in, bf16 MFMA, fp32/bf16 out.
// Tile 128(M) x 64(N). M multiple of 128, K multiple of 64, N ragged-guarded.
// permute: C row for logical row m is (m&7)*16 + (m>>3)  (m=t*8+b -> b*16+t)
// obf: store output as bf16 (ushort) instead of fp32.
// ---------------------------------------------------------------------------
__global__ __launch_bounds__(256)
void gemm_bt(const float* __restrict__ A, int lda,
             const float* __restrict__ Bm, int ldb,
             const float* __restrict__ bias,
             float* __restrict__ Cm, int ldc,
             int N, int K, int permute, int obf)
{
  __shared__ unsigned short Ash[128*72];
  __shared__ unsigned short Bsh[64*72];
  int tid = threadIdx.x;
  int mbase = blockIdx.x * 128;
  int nbase = blockIdx.y * 64;
  int wave = tid >> 6, lane = tid & 63;
  int wm = (wave & 1) * 64, wn = (wave >> 1) * 32;
  int fl = lane & 15, quad = lane >> 4;

  floatx4 acc[4][2];
  for (int i=0;i<4;i++) for(int j=0;j<2;j++) acc[i][j] = (floatx4)(0.0f);

  for (int kc = 0; kc < K; kc += 64) {
    float4 ra[8], rb[4];
#pragma unroll
    for (int i = 0; i < 8; ++i) {
      int idx = tid + i*256;
      int row = idx >> 4;
      int c4 = (idx & 15) << 2;
      ra[i] = *(const float4*)(A + (size_t)(mbase+row)*lda + kc + c4);
    }
#pragma unroll
    for (int i = 0; i < 4; ++i) {
      int idx = tid + i*256;
      int row = idx >> 4;
      int c4 = (idx & 15) << 2;
      int gn = nbase + row;
      if (gn < N) rb[i] = *(const float4*)(Bm + (size_t)gn*ldb + kc + c4);
      else { rb[i].x = 0.f; rb[i].y = 0.f; rb[i].z = 0.f; rb[i].w = 0.f; }
    }
    __syncthreads();
#pragma unroll
    for (int i = 0; i < 8; ++i) {
      int idx = tid + i*256;
      int o = (idx >> 4)*72 + ((idx & 15) << 2);
      Ash[o+0]=f2bf(ra[i].x); Ash[o+1]=f2bf(ra[i].y); Ash[o+2]=f2bf(ra[i].z); Ash[o+3]=f2bf(ra[i].w);
    }
#pragma unroll
    for (int i = 0; i < 4; ++i) {
      int idx = tid + i*256;
      int o = (idx >> 4)*72 + ((idx & 15) << 2);
      Bsh[o+0]=f2bf(rb[i].x); Bsh[o+1]=f2bf(rb[i].y); Bsh[o+2]=f2bf(rb[i].z); Bsh[o+3]=f2bf(rb[i].w);
    }
    __syncthreads();
#pragma unroll
    for (int ks = 0; ks < 2; ++ks) {
      short8 af[4], bfr[2];
      int ko = ks*32 + quad*8;
#pragma unroll
      for (int i=0;i<4;i++) af[i]  = *(const short8*)&Ash[(wm + i*16 + fl)*72 + ko];
#pragma unroll
      for (int j=0;j<2;j++) bfr[j] = *(const short8*)&Bsh[(wn + j*16 + fl)*72 + ko];
#pragma unroll
      for (int i=0;i<4;i++)
#pragma unroll
        for (int j=0;j<2;j++)
          acc[i][j] = __builtin_amdgcn_mfma_f32_16x16x32_bf16(af[i], bfr[j], acc[i][j], 0,0,0);
    }
    __syncthreads();
  }
  for (int i=0;i<4;i++){
    for (int j=0;j<2;j++){
      int nc = nbase + wn + j*16 + fl;
      if (nc >= N) continue;
      float bv = bias ? bias[nc] : 0.0f;
      for (int r=0;r<4;r++){
        int mg = mbase + wm + i*16 + quad*4 + r;
        int orow = permute ? ((mg & 7)*16 + (mg >> 3)) : mg;
        float v = acc[i][j][r] + bv;
        if (obf) ((unsigned short*)Cm)[(size_t)orow*ldc + nc] = f2bf(v);
        else     Cm[(size_t)orow*ldc + nc] = v;
      }
    }
  }
}

// ---------------------------------------------------------------------------
// Prologue P1: G = [ W_ih@xctx_w (640) | W_hh (512) ] in bf16  (2048 x 1152)
// blocks 0..639: 32x64 Wx tiles; blocks 640..1151: W_hh cast
// ---------------------------------------------------------------------------
__global__ __launch_bounds__(256) void p_wx(const float* __restrict__ wih,
    const float* __restrict__ whh, const float* __restrict__ xcw,
    unsigned short* __restrict__ G)
{
  int blk = blockIdx.x, tid = threadIdx.x;
  if (blk < 640) {
    int rt = blk / 10, ct = blk % 10;
    __shared__ float wl[32*128];
    __shared__ float xl[128*64];
    for (int i = tid; i < 4096; i += 256) {
      int r = i >> 7, k = i & 127;
      wl[i] = wih[(size_t)(rt*32+r)*128 + k];
    }
    for (int i = tid; i < 8192; i += 256) {
      int e = i >> 6, c = i & 63;
      xl[i] = xcw[(size_t)e*640 + ct*64 + c];
    }
    __syncthreads();
    for (int o = tid; o < 2048; o += 256) {
      int r = o >> 6, c = o & 63;
      float acc = 0.f;
      for (int e = 0; e < 128; ++e) acc += wl[r*128+e]*xl[e*64+c];
      G[(size_t)(rt*32+r)*1152 + ct*64 + c] = f2bf(acc);
    }
  } else {
    int idx = blk - 640;  // 0..511, 2048 elems each
    for (int q = 0; q < 2; ++q) {
      int n = idx*2048 + q*1024 + tid*4;
      int r = n >> 9, k = n & 511;
      float4 v = *(const float4*)(whh + n);
      ushort4_t s; s[0]=f2bf(v.x); s[1]=f2bf(v.y); s[2]=f2bf(v.z); s[3]=f2bf(v.w);
      *(ushort4_t*)(G + (size_t)r*1152 + 640 + k) = s;
    }
  }
}

// Prologue P2: gb[2048] = b_ih+b_hh+W_ih@xb ; q[640] = xctx_w^T@pw_x ; qb = pw_x@xb+pb
__global__ __launch_bounds__(256) void p_small(const float* __restrict__ wih,
    const float* __restrict__ bih, const float* __restrict__ bhh,
    const float* __restrict__ xb, const float* __restrict__ xcw,
    const float* __restrict__ pw, const float* __restrict__ pb,
    float* __restrict__ gb, float* __restrict__ q, float* __restrict__ qb)
{
  int blk = blockIdx.x, tid = threadIdx.x;
  if (blk < 8) {
    __shared__ float xbl[128];
    if (tid < 128) xbl[tid] = xb[tid];
    __syncthreads();
    int r = blk*256 + tid;
    const float* wr = wih + (size_t)r*128;
    float acc = bih[r] + bhh[r];
    for (int e = 0; e < 128; ++e) acc += wr[e]*xbl[e];
    gb[r] = acc;
  } else if (blk < 11) {
    int o = (blk-8)*256 + tid;
    if (o < 640) {
      float acc = 0.f;
      for (int e = 0; e < 128; ++e) acc += pw[1024+e]*xcw[(size_t)e*640 + o];
      q[o] = acc;
    }
  } else if (tid == 0) {
    float acc = 0.f;
    for (int e = 0; e < 128; ++e) acc += pw[1024+e]*xb[e];
    qb[0] = acc + pb[0];
  }
}

// Prologue P3: enc -> bf16 (blocks 0..799) ; ew[:, :512] -> bf16 (blocks 800..927)
__global__ __launch_bounds__(256) void p_cast(const float* __restrict__ enc,
    const float* __restrict__ ew, unsigned short* __restrict__ encb,
    unsigned short* __restrict__ ewhb)
{
  int blk = blockIdx.x, tid = threadIdx.x;
  if (blk < 800) {
    for (int q = 0; q < 2; ++q) {
      size_t n = (size_t)blk*2048 + q*1024 + tid*4;
      float4 v = *(const float4*)(enc + n);
      ushort4_t s; s[0]=f2bf(v.x); s[1]=f2bf(v.y); s[2]=f2bf(v.z); s[3]=f2bf(v.w);
      *(ushort4_t*)(encb + n) = s;
    }
  } else {
    int idx = blk - 800;  // 0..127, 2048 elems each over 262144
    for (int q = 0; q < 2; ++q) {
      size_t n = (size_t)idx*2048 + q*1024 + tid*4;
      int p = (int)(n >> 9), k = (int)(n & 511);
      float4 v = *(const float4*)(ew + (size_t)p*1024 + k);
      ushort4_t s; s[0]=f2bf(v.x); s[1]=f2bf(v.y); s[2]=f2bf(v.z); s[3]=f2bf(v.w);
      *(ushort4_t*)(ewhb + n) = s;
    }
  }
}

// ---------------------------------------------------------------------------
// S1: gates = G @ [emb;ctx(t-1);h(t-1)] + gb -> LSTM cell -> h(t),c(t)
// 256 blocks x 256 thr. Block owns 2 j's x 4 gates = 8 rows, all 8 b.
// ---------------------------------------------------------------------------
__global__ __launch_bounds__(256) void s1_gates(
    const unsigned short* __restrict__ G, const float* __restrict__ gb,
    const float* __restrict__ emb, const float* __restrict__ context,
    const float* __restrict__ h0, const float* __restrict__ c0,
    float* __restrict__ A1, float* __restrict__ c_cur, int t)
{
  __shared__ float u[8*1156];
  __shared__ float part[256];
  __shared__ float gl[64];
  int tid = threadIdx.x, blk = blockIdx.x;
  for (int b = 0; b < 8; ++b) {
    const float* ctxp = t ? (A1 + ((size_t)((t-1)*8+b))*1024 + 512) : (context + b*512);
    const float* hpv  = t ? (A1 + ((size_t)((t-1)*8+b))*1024)       : (h0 + b*512);
    for (int k = tid; k < 1152; k += 256) {
      float val;
      if (k < 128)      val = emb[(size_t)(b*16+t)*128 + k];
      else if (k < 640) val = ctxp[k-128];
      else              val = hpv[k-640];
      u[b*1156 + k] = val;
    }
  }
  __syncthreads();
  int dot = tid >> 2, kq = tid & 3;   // 64 dots (8 rows x 8 b), 4-way k-split
  int rr = dot >> 3, b = dot & 7;     // rr = gate*2+jj
  int gate = rr >> 1, jj = rr & 1;
  int r = gate*512 + blk*2 + jj;
  const unsigned short* gp = G + (size_t)r*1152 + kq*8;
  const float* up = u + b*1156 + kq*8;
  float acc = 0.f;
#pragma unroll 4
  for (int i = 0; i < 36; ++i) {      // 36 chunks of 8, stride 32 (kq-interleave)
    ushort8_t w8 = *(const ushort8_t*)(gp + i*32);
    float4 u0 = *(const float4*)(up + i*32);
    float4 u1 = *(const float4*)(up + i*32 + 4);
    acc += bfu(w8[0])*u0.x + bfu(w8[1])*u0.y + bfu(w8[2])*u0.z + bfu(w8[3])*u0.w
         + bfu(w8[4])*u1.x + bfu(w8[5])*u1.y + bfu(w8[6])*u1.z + bfu(w8[7])*u1.w;
  }
  part[tid] = acc;
  __syncthreads();
  if (tid < 64) {
    int rr2 = tid >> 3;
    int r2 = (rr2 >> 1)*512 + blk*2 + (rr2 & 1);
    gl[tid] = part[tid*4] + part[tid*4+1] + part[tid*4+2] + part[tid*4+3] + gb[r2];
  }
  __syncthreads();
  if (tid < 16) {
    int jj2 = tid >> 3, b2 = tid & 7;
    float gi = gl[(0*2+jj2)*8 + b2];
    float gf = gl[(1*2+jj2)*8 + b2];
    float gg = gl[(2*2+jj2)*8 + b2];
    float go = gl[(3*2+jj2)*8 + b2];
    int j = blk*2 + jj2;
    float cp = t ? c_cur[b2*512+j] : c0[b2*512+j];
    float cn = sigm(gf)*cp + sigm(gi)*tanhf(gg);
    float hn = sigm(go)*tanhf(cn);
    c_cur[b2*512+j] = cn;
    A1[((size_t)(t*8+b2))*1024 + j] = hn;
  }
}

// S2: hp[b,p] = eb[p] + ewh@h(t) ; 64 blocks x 256 thr (8 p-rows x 8 b each)
__global__ __launch_bounds__(256) void s2_hp(
    const unsigned short* __restrict__ ewhb, const float* __restrict__ eb,
    const float* __restrict__ A1, float* __restrict__ hp, int t)
{
  __shared__ float hl[8*516];
  __shared__ float part[256];
  int tid = threadIdx.x, pc = blockIdx.x;
  for (int b = 0; b < 8; ++b)
    for (int k = tid; k < 512; k += 256)
      hl[b*516 + k] = A1[((size_t)(t*8+b))*1024 + k];
  __syncthreads();
  int dot = tid >> 2, kq = tid & 3;
  int rr = dot >> 3, b = dot & 7;
  int p = pc*8 + rr;
  const unsigned short* wp = ewhb + (size_t)p*512 + kq*16;
  const float* hh = hl + b*516 + kq*16;
  float acc = 0.f;
#pragma unroll
  for (int i = 0; i < 8; ++i) {       // 8 chunks of 16, stride 64
    ushort8_t wa = *(const ushort8_t*)(wp + i*64);
    ushort8_t wb = *(const ushort8_t*)(wp + i*64 + 8);
    float4 h0v = *(const float4*)(hh + i*64);
    float4 h1v = *(const float4*)(hh + i*64 + 4);
    float4 h2v = *(const float4*)(hh + i*64 + 8);
    float4 h3v = *(const float4*)(hh + i*64 + 12);
    acc += bfu(wa[0])*h0v.x + bfu(wa[1])*h0v.y + bfu(wa[2])*h0v.z + bfu(wa[3])*h0v.w
         + bfu(wa[4])*h1v.x + bfu(wa[5])*h1v.y + bfu(wa[6])*h1v.z + bfu(wa[7])*h1v.w
         + bfu(wb[0])*h2v.x + bfu(wb[1])*h2v.y + bfu(wb[2])*h2v.z + bfu(wb[3])*h2v.w
         + bfu(wb[4])*h3v.x + bfu(wb[5])*h3v.y + bfu(wb[6])*h3v.z + bfu(wb[7])*h3v.w;
  }
  part[tid] = acc;
  __syncthreads();
  if (tid < 64) {
    int rr2 = tid >> 3, b2 = tid & 7;
    int p2 = pc*8 + rr2;
    hp[b2*512 + p2] = eb[p2] + part[tid*4] + part[tid*4+1] + part[tid*4+2] + part[tid*4+3];
  }
}

// S3: e[b,s] = sum_h tanh(hp + encp + cov*covw) * v ; 128 blocks (8 b x 16 sc)
__global__ __launch_bounds__(256) void s3_e(
    const unsigned short* __restrict__ encpb, const float* __restrict__ hp,
    const float* __restrict__ vvec, const float* __restrict__ covw,
    const float* __restrict__ coverage, const float* __restrict__ out6,
    float* __restrict__ evec, int t)
{
  int tid = threadIdx.x;
  int b = blockIdx.x >> 4, sc = blockIdx.x & 15;
  int w = tid >> 6, lane = tid & 63;
  int h0i = lane*8;
  float hpv[8], vv[8], cw[8];
  {
    const float* hpp = hp + b*512 + h0i;
    float4 a0 = *(const float4*)(hpp), a1 = *(const float4*)(hpp+4);
    hpv[0]=a0.x; hpv[1]=a0.y; hpv[2]=a0.z; hpv[3]=a0.w;
    hpv[4]=a1.x; hpv[5]=a1.y; hpv[6]=a1.z; hpv[7]=a1.w;
    float4 v0 = *(const float4*)(vvec+h0i), v1 = *(const float4*)(vvec+h0i+4);
    vv[0]=v0.x; vv[1]=v0.y; vv[2]=v0.z; vv[3]=v0.w;
    vv[4]=v1.x; vv[5]=v1.y; vv[6]=v1.z; vv[7]=v1.w;
    float4 c0v = *(const float4*)(covw+h0i), c1v = *(const float4*)(covw+h0i+4);
    cw[0]=c0v.x; cw[1]=c0v.y; cw[2]=c0v.z; cw[3]=c0v.w;
    cw[4]=c1v.x; cw[5]=c1v.y; cw[6]=c1v.z; cw[7]=c1v.w;
  }
  const float* covp = t ? (out6 + ((size_t)(b*16 + t-1))*400) : (coverage + b*400);
  for (int sl = w; sl < 25; sl += 4) {
    int s = sc*25 + sl;
    float cv = covp[s];
    const unsigned short* ep = encpb + ((size_t)(b*400+s))*512 + h0i;
    ushort8_t e8 = *(const ushort8_t*)ep;
    float acc = 0.f;
#pragma unroll
    for (int i = 0; i < 8; ++i)
      acc += tanhf(hpv[i] + bfu(e8[i]) + cv*cw[i]) * vv[i];
    for (int off = 32; off > 0; off >>= 1) acc += __shfl_down(acc, off);
    if (lane == 0) evec[b*400 + s] = acc;
  }
}

// S4: softmax(+mask renorm) + coverage + ctx ; 32 blocks (8 b x 4 col-chunks of 128)
__global__ __launch_bounds__(256) void s4_soft_ctx(
    const float* __restrict__ evec, const float* __restrict__ masks,
    const float* __restrict__ coverage, const unsigned short* __restrict__ encb,
    float* __restrict__ A1, float* __restrict__ out, int t)
{
  int tid = threadIdx.x;
  int b = blockIdx.x >> 2, cc = blockIdx.x & 3;
  __shared__ float evl[400], prl[400];
  __shared__ float red[18];
  __shared__ float cpx[256], cpy[256];
  for (int i = tid; i < 400; i += 256) evl[i] = evec[b*400 + i];
  __syncthreads();
  int w = tid >> 6, lane = tid & 63;
  float v1 = evl[tid];
  float v2 = (tid < 144) ? evl[256+tid] : -1e30f;
  float mx = fmaxf(v1, v2);
  for (int off = 32; off > 0; off >>= 1) mx = fmaxf(mx, __shfl_down(mx, off));
  if (lane == 0) red[w] = mx;
  __syncthreads();
  if (tid == 0) red[16] = fmaxf(fmaxf(red[0],red[1]), fmaxf(red[2],red[3]));
  __syncthreads();
  float smx = red[16];
  float m1 = masks[b*400 + tid];
  float m2 = (tid < 144) ? masks[b*400 + 256 + tid] : 0.f;
  float p1 = __expf(v1 - smx);
  float p2 = (tid < 144) ? __expf(v2 - smx) : 0.f;
  float pm1 = p1*m1, pm2 = p2*m2;
  float s1 = p1 + p2, s2 = pm1 + pm2;
  for (int off = 32; off > 0; off >>= 1) { s1 += __shfl_down(s1,off); s2 += __shfl_down(s2,off); }
  if (lane == 0) { red[w] = s1; red[4+w] = s2; }
  __syncthreads();
  if (tid == 0) {
    float d1 = red[0]+red[1]+red[2]+red[3];
    float d2 = red[4]+red[5]+red[6]+red[7];
    red[17] = d2 + 1e-12f*d1;
  }
  __syncthreads();
  float denom = red[17];
  prl[tid] = pm1 / denom;
  if (tid < 144) prl[256+tid] = pm2 / denom;
  __syncthreads();
  if (cc == 0) {
    const float* covp = t ? (out + O6 + ((size_t)(b*16 + t-1))*400) : (coverage + b*400);
    size_t o = ((size_t)(b*16 + t))*400;
    out[O4 + o + tid] = prl[tid];
    out[O6 + o + tid] = covp[tid] + prl[tid];
    if (tid < 144) {
      out[O4 + o + 256 + tid] = prl[256+tid];
      out[O6 + o + 256 + tid] = covp[256+tid] + prl[256+tid];
    }
  }
  // ctx: 4 s-groups of 100 x 64 col-pairs
  int sg = tid >> 6, cp = tid & 63;
  int c = cc*128 + cp*2;
  float ax = 0.f, ay = 0.f;
  const unsigned short* ep = encb + ((size_t)(b*400 + sg*100))*512 + c;
  for (int s3 = 0; s3 < 100; ++s3) {
    float pr = prl[sg*100 + s3];
    unsigned int uu = *(const unsigned int*)(ep + (size_t)s3*512);
    ax += pr * bfu((unsigned short)(uu & 0xffffu));
    ay += pr * bfu((unsigned short)(uu >> 16));
  }
  cpx[tid] = ax; cpy[tid] = ay;
  __syncthreads();
  if (tid < 64) {
    float sx = cpx[tid] + cpx[64+tid] + cpx[128+tid] + cpx[192+tid];
    float sy = cpy[tid] + cpy[64+tid] + cpy[128+tid] + cpy[192+tid];
    size_t row = ((size_t)(t*8+b))*1024 + 512 + cc*128 + tid*2;
    A1[row] = sx; A1[row+1] = sy;
  }
}

// Epilogue: pgen for all (t,b) + out1/2/3/5 copies
__global__ __launch_bounds__(256) void e_pgen(
    const float* __restrict__ A1, const float* __restrict__ c_cur,
    const float* __restrict__ emb, const float* __restrict__ context,
    const float* __restrict__ pw, const float* __restrict__ q,
    const float* __restrict__ qb, float* __restrict__ pgen, float* __restrict__ out)
{
  int blk = blockIdx.x, tid = threadIdx.x;
  if (blk < 128) {
    int m = blk, t = m >> 3, b = m & 7;
    const float* ctxT = A1 + (size_t)m*1024 + 512;
    const float* hT   = A1 + (size_t)m*1024;
    const float* embp = emb + (size_t)(b*16+t)*128;
    const float* ctxP = t ? (A1 + ((size_t)((t-1)*8+b))*1024 + 512) : (context + b*512);
    float acc = 0.f;
    for (int k = tid; k < 512; k += 256)
      acc += pw[k]*ctxT[k] + pw[512+k]*hT[k] + q[128+k]*ctxP[k];
    if (tid < 128) acc += q[tid]*embp[tid];
    for (int off = 32; off > 0; off >>= 1) acc += __shfl_down(acc, off);
    __shared__ float red[4];
    if (!(tid & 63)) red[tid>>6] = acc;
    __syncthreads();
    if (tid == 0) {
      float pg = sigm(red[0]+red[1]+red[2]+red[3] + qb[0]);
      pgen[m] = pg;
      if (t == 15) out[O5 + b] = pg;
    }
  } else if (blk == 128) {
    for (int i = tid; i < 4096; i += 256) {
      int b = i >> 9, j = i & 511;
      out[O1 + i] = A1[((size_t)(120+b))*1024 + 512 + j];
    }
  } else if (blk == 129) {
    for (int i = tid; i < 4096; i += 256) {
      int b = i >> 9, j = i & 511;
      out[O2 + i] = A1[((size_t)(120+b))*1024 + j];
    }
  } else {
    for (int i = tid; i < 4096; i += 256) out[O3 + i] = c_cur[i];
  }
}

// in-place vocab softmax + p_gen scale + OOV cols + copy-mechanism scatter
__global__ __launch_bounds__(256) void k_final(
  float* __restrict__ out, const float* __restrict__ pgen,
  const float* __restrict__ ez, const int* __restrict__ extidx)
{
  int m = blockIdx.x;           // m = t*8+b
  int b = m & 7, t = m >> 3;
  float* row = out + ((size_t)(b*TT + t))*VE;
  int tid = threadIdx.x;
  __shared__ float red[4];
  __shared__ float smx, ssum;
  float mx = -1e30f;
  for (int v2 = tid; v2 < VV; v2 += 256) mx = fmaxf(mx, row[v2]);
  for (int off=32; off>0; off>>=1) mx = fmaxf(mx, __shfl_down(mx, off));
  int wave = tid>>6, lane = tid&63;
  if (lane==0) red[wave] = mx;
  __syncthreads();
  if (tid==0){ float m2=red[0]; for(int i=1;i<4;i++) m2=fmaxf(m2,red[i]); smx=m2; }
  __syncthreads();
  float mxv = smx;
  float sm = 0.0f;
  for (int v2 = tid; v2 < VV; v2 += 256) {
    float e2 = __expf(row[v2] - mxv);
    row[v2] = e2;
    sm += e2;
  }
  for (int off=32; off>0; off>>=1) sm += __shfl_down(sm, off);
  if (lane==0) red[wave] = sm;
  __syncthreads();
  if (tid==0){ float s2=0; for(int i=0;i<4;i++) s2+=red[i]; ssum=s2; }
  __syncthreads();
  float pg = pgen[m];
  float scale = pg / ssum;
  for (int v2 = tid; v2 < VV; v2 += 256) row[v2] *= scale;
  for (int v2 = VV + tid; v2 < VE; v2 += 256) row[v2] = ez[b*OOVn + (v2-VV)];
  __syncthreads();
  float onem = 1.0f - pg;
  const float* pr = out + O4 + ((size_t)(b*TT+t))*SS;
  for (int s2 = tid; s2 < SS; s2 += 256) {
    int ix = extidx[b*SS + s2];
    atomicAdd(&row[ix], onem * pr[s2]);
  }
}

extern "C" void kernel_launch(void* const* d_in, const int* in_sizes, int n_in,
                              void* d_out, int out_size, void* d_ws, size_t ws_size,
                              hipStream_t stream)
{
  (void)in_sizes; (void)n_in; (void)out_size; (void)ws_size;
  const float* emb      = (const float*)d_in[0];
  const float* context  = (const float*)d_in[1];
  const float* h0       = (const float*)d_in[2];
  const float* c0       = (const float*)d_in[3];
  const float* enc      = (const float*)d_in[4];
  const float* masks    = (const float*)d_in[5];
  const float* ez       = (const float*)d_in[6];
  const int*   extidx   = (const int*)d_in[7];
  const float* coverage = (const float*)d_in[8];
  const float* wih      = (const float*)d_in[9];
  const float* whh      = (const float*)d_in[10];
  const float* bih      = (const float*)d_in[11];
  const float* bhh      = (const float*)d_in[12];
  const float* covw     = (const float*)d_in[13];
  const float* ew       = (const float*)d_in[14];
  const float* eb       = (const float*)d_in[15];
  const float* vvec     = (const float*)d_in[16];
  const float* xw       = (const float*)d_in[17];
  const float* xb       = (const float*)d_in[18];
  const float* aw       = (const float*)d_in[19];
  const float* ab       = (const float*)d_in[20];
  const float* vw       = (const float*)d_in[21];
  const float* vb       = (const float*)d_in[22];
  const float* pw       = (const float*)d_in[23];
  const float* pb       = (const float*)d_in[24];
  float* out = (float*)d_out;

  float* ws = (float*)d_ws;
  float* A1         = ws;                    // 128 x 1024 : [h | ctx] per (t,b)
  float* c_cur      = A1 + 131072;           // 8 x 512
  float* hp         = c_cur + 4096;          // 8 x 512
  float* evec       = hp + 4096;             // 8 x 400
  float* attnd_feat = evec + 3200;           // 128 x 512
  float* pgen       = attnd_feat + 65536;    // 128
  float* gb         = pgen + 128;            // 2048
  float* q          = gb + 2048;             // 640
  float* qb         = q + 640;               // 1

  unsigned short* G     = (unsigned short*)(out + G_OFF);
  unsigned short* encb  = (unsigned short*)(out + ENCB_OFF);
  unsigned short* ewhb  = (unsigned short*)(out + EWHB_OFF);
  unsigned short* encpb = (unsigned short*)(out + ENCP_OFF);

  // Prologue (scratch lives in out0 region; dead until logits GEMM)
  p_wx<<<1152, 256, 0, stream>>>(wih, whh, xw, G);
  p_small<<<12, 256, 0, stream>>>(wih, bih, bhh, xb, xw, pw, pb, gb, q, qb);
  p_cast<<<928, 256, 0, stream>>>(enc, ew, encb, ewhb);
  // encp_bf = enc @ energy_w[:,512:].T  (bf16 out)
  gemm_bt<<<dim3(25,8), 256, 0, stream>>>(enc, 512, ew + 512, 1024,
      (const float*)nullptr, (float*)encpb, 512, 512, 512, 0, 1);

  for (int t = 0; t < TT; ++t) {
    s1_gates<<<256, 256, 0, stream>>>(G, gb, emb, context, h0, c0, A1, c_cur, t);
    s2_hp<<<64, 256, 0, stream>>>(ewhb, eb, A1, hp, t);
    s3_e<<<128, 256, 0, stream>>>(encpb, hp, vvec, covw, coverage, out + O6, evec, t);
    s4_soft_ctx<<<32, 256, 0, stream>>>(evec, masks, coverage, encb, A1, out, t);
  }

  e_pgen<<<131, 256, 0, stream>>>(A1, c_cur, emb, context, pw, q, qb, pgen, out);
  // attnd_feat = [h|ctx] @ attnd_w.T + attnd_b
  gemm_bt<<<dim3(1,8), 256, 0, stream>>>(A1, 1024, aw, 1024, ab, attnd_feat, 512, 512, 1024, 0, 0);
  // logits (all 16 steps batched) = attnd_feat @ vocab_w.T + vocab_b -> out rows (b*16+t)
  gemm_bt<<<dim3(1,782), 256, 0, stream>>>(attnd_feat, 512, vw, 512, vb, out, VE, VV, 512, 1, 0);
  k_final<<<128, 256, 0, stream>>>(out, pgen, ez, extidx);
}

// Round 4
// 805.122 us; speedup vs baseline: 2.7445x; 1.2389x over previous
//
#include <hip/hip_runtime.h>
#include <math.h>

#define BB 8
#define TT 16
#define SS 400
#define HH 512
#define EE 128
#define VV 50000
#define VE 50050
#define OOVn 50

// output offsets (floats)
#define O1 6406400
#define O2 6410496
#define O3 6414592
#define O4 6418688
#define O5 6469888
#define O6 6469896

// scratch inside out0 logits region (float offsets; dead until gemm_logits)
#define G_OFF    0          // 2048x1152 ushort = 1,179,648 f
#define EWHB_OFF 1179648    // 512x512  ushort =   131,072 f -> ends 1,310,720
#define ENCG_OFF 1310720    // 8x2048x400 ushort = 3,276,800 f -> ends 4,587,520
#define WXF_OFF  4600000    // 2048x512 fp32 = 1,048,576 f (dead after encG gemm)
#define ENCP_OFF 4600000    // 3200x512 ushort = 819,200 f (overwrites WXF - ok)
#define PM_OFF   5700000    // 16x8x400 fp32 = 51,200 f -> ends 5,751,200

typedef __attribute__((ext_vector_type(4))) float floatx4;
typedef __attribute__((ext_vector_type(8))) short short8;
typedef __attribute__((ext_vector_type(8))) unsigned short ushort8_t;
typedef __attribute__((ext_vector_type(4))) unsigned short ushort4_t;

__device__ __forceinline__ float sigm(float x){ return 1.0f/(1.0f+__expf(-x)); }
__device__ __forceinline__ float ftanh(float x){
  float e = __expf(2.0f*x); return 1.0f - 2.0f/(e + 1.0f);
}
__device__ __forceinline__ unsigned short f2bf(float f){
  union { float f; unsigned int u; } v; v.f = f;
  unsigned int u = v.u;
  return (unsigned short)((u + 0x7FFFu + ((u >> 16) & 1u)) >> 16);
}
__device__ __forceinline__ float bfu(unsigned short u){
  union { unsigned int i; float f; } v; v.i = ((unsigned int)u) << 16; return v.f;
}

// ---------------------------------------------------------------------------
// GEMM: C[M,N] = A[M,K] @ B[N,K]^T (+bias). fp32 in, bf16 MFMA, fp32/bf16 out.
// Tile 128(M) x 64(N). Optional batch (blockIdx.z) strides for B and C.
// ---------------------------------------------------------------------------
__global__ __launch_bounds__(256)
void gemm_bt(const float* __restrict__ A, int lda,
             const float* __restrict__ Bm, int ldb,
             const float* __restrict__ bias,
             float* __restrict__ Cm, int ldc,
             int N, int K, int permute, int obf,
             long bsB, long bsC)
{
  __shared__ unsigned short Ash[128*72];
  __shared__ unsigned short Bsh[64*72];
  int tid = threadIdx.x;
  int mbase = blockIdx.x * 128;
  int nbase = blockIdx.y * 64;
  long z = blockIdx.z;
  const float* Bz = Bm + z*bsB;
  int wave = tid >> 6, lane = tid & 63;
  int wm = (wave & 1) * 64, wn = (wave >> 1) * 32;
  int fl = lane & 15, quad = lane >> 4;

  floatx4 acc[4][2];
  for (int i=0;i<4;i++) for(int j=0;j<2;j++) acc[i][j] = (floatx4)(0.0f);

  for (int kc = 0; kc < K; kc += 64) {
    float4 ra[8], rb[4];
#pragma unroll
    for (int i = 0; i < 8; ++i) {
      int idx = tid + i*256;
      int row = idx >> 4;
      int c4 = (idx & 15) << 2;
      ra[i] = *(const float4*)(A + (size_t)(mbase+row)*lda + kc + c4);
    }
#pragma unroll
    for (int i = 0; i < 4; ++i) {
      int idx = tid + i*256;
      int row = idx >> 4;
      int c4 = (idx & 15) << 2;
      int gn = nbase + row;
      if (gn < N) rb[i] = *(const float4*)(Bz + (size_t)gn*ldb + kc + c4);
      else { rb[i].x = 0.f; rb[i].y = 0.f; rb[i].z = 0.f; rb[i].w = 0.f; }
    }
    __syncthreads();
#pragma unroll
    for (int i = 0; i < 8; ++i) {
      int idx = tid + i*256;
      int o = (idx >> 4)*72 + ((idx & 15) << 2);
      Ash[o+0]=f2bf(ra[i].x); Ash[o+1]=f2bf(ra[i].y); Ash[o+2]=f2bf(ra[i].z); Ash[o+3]=f2bf(ra[i].w);
    }
#pragma unroll
    for (int i = 0; i < 4; ++i) {
      int idx = tid + i*256;
      int o = (idx >> 4)*72 + ((idx & 15) << 2);
      Bsh[o+0]=f2bf(rb[i].x); Bsh[o+1]=f2bf(rb[i].y); Bsh[o+2]=f2bf(rb[i].z); Bsh[o+3]=f2bf(rb[i].w);
    }
    __syncthreads();
#pragma unroll
    for (int ks = 0; ks < 2; ++ks) {
      short8 af[4], bfr[2];
      int ko = ks*32 + quad*8;
#pragma unroll
      for (int i=0;i<4;i++) af[i]  = *(const short8*)&Ash[(wm + i*16 + fl)*72 + ko];
#pragma unroll
      for (int j=0;j<2;j++) bfr[j] = *(const short8*)&Bsh[(wn + j*16 + fl)*72 + ko];
#pragma unroll
      for (int i=0;i<4;i++)
#pragma unroll
        for (int j=0;j<2;j++)
          acc[i][j] = __builtin_amdgcn_mfma_f32_16x16x32_bf16(af[i], bfr[j], acc[i][j], 0,0,0);
    }
    __syncthreads();
  }
  for (int i=0;i<4;i++){
    for (int j=0;j<2;j++){
      int nc = nbase + wn + j*16 + fl;
      if (nc >= N) continue;
      float bv = bias ? bias[nc] : 0.0f;
      for (int r=0;r<4;r++){
        int mg = mbase + wm + i*16 + quad*4 + r;
        int orow = permute ? ((mg & 7)*16 + (mg >> 3)) : mg;
        float v = acc[i][j][r] + bv;
        long ci = (long)orow*ldc + nc + z*bsC;
        if (obf) ((unsigned short*)Cm)[ci] = f2bf(v);
        else     Cm[ci] = v;
      }
    }
  }
}

// ---------------------------------------------------------------------------
// gemm_logits: out[orow, 0:50000] = exp(attnd_bf @ vocab_w^T + vb), + rowsum.
// M=128 fixed, A bf16 (attnd_bf), B fp32 (vocab_w). grid = 782 (64-col tiles).
// ---------------------------------------------------------------------------
__global__ __launch_bounds__(256)
void gemm_logits(const unsigned short* __restrict__ Abf,
                 const float* __restrict__ Bm, const float* __restrict__ bias,
                 float* __restrict__ out, float* __restrict__ rowsum)
{
  __shared__ unsigned short Ash[128*72];
  __shared__ unsigned short Bsh[64*72];
  __shared__ float rowpart[128];
  int tid = threadIdx.x;
  int nbase = blockIdx.x * 64;
  int wave = tid >> 6, lane = tid & 63;
  int wm = (wave & 1) * 64, wn = (wave >> 1) * 32;
  int fl = lane & 15, quad = lane >> 4;

  floatx4 acc[4][2];
  for (int i=0;i<4;i++) for(int j=0;j<2;j++) acc[i][j] = (floatx4)(0.0f);
  if (tid < 128) rowpart[tid] = 0.f;

  for (int kc = 0; kc < 512; kc += 64) {
    ushort8_t raa[4];
    float4 rb[4];
#pragma unroll
    for (int i = 0; i < 4; ++i) {
      int idx = tid + i*256;
      int row = idx >> 3;
      int c8 = (idx & 7) << 3;
      raa[i] = *(const ushort8_t*)(Abf + (size_t)row*512 + kc + c8);
    }
#pragma unroll
    for (int i = 0; i < 4; ++i) {
      int idx = tid + i*256;
      int row = idx >> 4;
      int c4 = (idx & 15) << 2;
      int gn = nbase + row;
      if (gn < VV) rb[i] = *(const float4*)(Bm + (size_t)gn*512 + kc + c4);
      else { rb[i].x = 0.f; rb[i].y = 0.f; rb[i].z = 0.f; rb[i].w = 0.f; }
    }
    __syncthreads();
#pragma unroll
    for (int i = 0; i < 4; ++i) {
      int idx = tid + i*256;
      int o = (idx >> 3)*72 + ((idx & 7) << 3);
      *(ushort8_t*)&Ash[o] = raa[i];
    }
#pragma unroll
    for (int i = 0; i < 4; ++i) {
      int idx = tid + i*256;
      int o = (idx >> 4)*72 + ((idx & 15) << 2);
      Bsh[o+0]=f2bf(rb[i].x); Bsh[o+1]=f2bf(rb[i].y); Bsh[o+2]=f2bf(rb[i].z); Bsh[o+3]=f2bf(rb[i].w);
    }
    __syncthreads();
#pragma unroll
    for (int ks = 0; ks < 2; ++ks) {
      short8 af[4], bfr[2];
      int ko = ks*32 + quad*8;
#pragma unroll
      for (int i=0;i<4;i++) af[i]  = *(const short8*)&Ash[(wm + i*16 + fl)*72 + ko];
#pragma unroll
      for (int j=0;j<2;j++) bfr[j] = *(const short8*)&Bsh[(wn + j*16 + fl)*72 + ko];
#pragma unroll
      for (int i=0;i<4;i++)
#pragma unroll
        for (int j=0;j<2;j++)
          acc[i][j] = __builtin_amdgcn_mfma_f32_16x16x32_bf16(af[i], bfr[j], acc[i][j], 0,0,0);
    }
    __syncthreads();
  }
  for (int i=0;i<4;i++){
    for (int r=0;r<4;r++){
      int mg = wm + i*16 + quad*4 + r;
      int orow = (mg & 7)*16 + (mg >> 3);
      float rs = 0.f;
      for (int j=0;j<2;j++){
        int nc = nbase + wn + j*16 + fl;
        if (nc < VV) {
          float e = __expf(acc[i][j][r] + bias[nc]);
          out[(size_t)orow*VE + nc] = e;
          rs += e;
        }
      }
      atomicAdd(&rowpart[mg], rs);
    }
  }
  __syncthreads();
  if (tid < 128) {
    int orow = (tid & 7)*16 + (tid >> 3);
    atomicAdd(&rowsum[orow], rowpart[tid]);
  }
}

// ---------------------------------------------------------------------------
// Prologue P1: G = [Wx = W_ih@xctx_w (640) | W_hh (512)] bf16; also Wx_ctx fp32
// ---------------------------------------------------------------------------
__global__ __launch_bounds__(256) void p_wx(const float* __restrict__ wih,
    const float* __restrict__ whh, const float* __restrict__ xcw,
    unsigned short* __restrict__ G, float* __restrict__ wxf)
{
  int blk = blockIdx.x, tid = threadIdx.x;
  if (blk < 640) {
    int rt = blk / 10, ct = blk % 10;
    __shared__ float wl[32*128];
    __shared__ float xl[128*64];
    for (int i = tid; i < 4096; i += 256) {
      int r = i >> 7, k = i & 127;
      wl[i] = wih[(size_t)(rt*32+r)*128 + k];
    }
    for (int i = tid; i < 8192; i += 256) {
      int e = i >> 6, c = i & 63;
      xl[i] = xcw[(size_t)e*640 + ct*64 + c];
    }
    __syncthreads();
    for (int o = tid; o < 2048; o += 256) {
      int r = o >> 6, c = o & 63;
      float acc = 0.f;
      for (int e = 0; e < 128; ++e) acc += wl[r*128+e]*xl[e*64+c];
      G[(size_t)(rt*32+r)*1152 + ct*64 + c] = f2bf(acc);
      int col = ct*64 + c;
      if (col >= 128) wxf[(size_t)(rt*32+r)*512 + col - 128] = acc;
    }
  } else {
    int idx = blk - 640;  // 0..511
    for (int q = 0; q < 2; ++q) {
      int n = idx*2048 + q*1024 + tid*4;
      int r = n >> 9, k = n & 511;
      float4 v = *(const float4*)(whh + n);
      ushort4_t s; s[0]=f2bf(v.x); s[1]=f2bf(v.y); s[2]=f2bf(v.z); s[3]=f2bf(v.w);
      *(ushort4_t*)(G + (size_t)r*1152 + 640 + k) = s;
    }
  }
}

// Prologue P2: gb = b_ih+b_hh+W_ih@xb ; q = xctx_w^T@pw_x ; qb ; zero d1/d2
__global__ __launch_bounds__(256) void p_small(const float* __restrict__ wih,
    const float* __restrict__ bih, const float* __restrict__ bhh,
    const float* __restrict__ xb, const float* __restrict__ xcw,
    const float* __restrict__ pw, const float* __restrict__ pb,
    float* __restrict__ gb, float* __restrict__ q, float* __restrict__ qb,
    float* __restrict__ d1, float* __restrict__ d2)
{
  int blk = blockIdx.x, tid = threadIdx.x;
  if (blk < 8) {
    __shared__ float xbl[128];
    if (tid < 128) xbl[tid] = xb[tid];
    __syncthreads();
    int r = blk*256 + tid;
    const float* wr = wih + (size_t)r*128;
    float acc = bih[r] + bhh[r];
    for (int e = 0; e < 128; ++e) acc += wr[e]*xbl[e];
    gb[r] = acc;
  } else if (blk < 11) {
    int o = (blk-8)*256 + tid;
    if (o < 640) {
      float acc = 0.f;
      for (int e = 0; e < 128; ++e) acc += pw[1024+e]*xcw[(size_t)e*640 + o];
      q[o] = acc;
    }
  } else {
    if (tid == 0) {
      float acc = 0.f;
      for (int e = 0; e < 128; ++e) acc += pw[1024+e]*xb[e];
      qb[0] = acc + pb[0];
    }
    if (tid < 128) { d1[tid] = 0.f; d2[tid] = 0.f; }
  }
}

// Prologue P3: ew[:, :512] -> bf16
__global__ __launch_bounds__(256) void p_cast(const float* __restrict__ ew,
    unsigned short* __restrict__ ewhb)
{
  int blk = blockIdx.x, tid = threadIdx.x;
  for (int q = 0; q < 2; ++q) {
    size_t n = (size_t)blk*2048 + q*1024 + tid*4;
    int p = (int)(n >> 9), k = (int)(n & 511);
    float4 v = *(const float4*)(ew + (size_t)p*1024 + k);
    ushort4_t s; s[0]=f2bf(v.x); s[1]=f2bf(v.y); s[2]=f2bf(v.z); s[3]=f2bf(v.w);
    *(ushort4_t*)(ewhb + n) = s;
  }
}

// ---------------------------------------------------------------------------
// S1: gates[r,b] = gb + G_emb@emb + G_h@h(t-1) + ctx-part -> LSTM -> h(t),c(t)
//   ctx-part: t==0: G_ctx @ context;  t>=1: sum_s probs(t-1)[s] * encG[b,r,s]
// Also (blk<8): writes out4/out6 for step t-1.
// ---------------------------------------------------------------------------
__global__ __launch_bounds__(256) void s1g(
    const unsigned short* __restrict__ G, const unsigned short* __restrict__ encG,
    const float* __restrict__ gb,
    const float* __restrict__ emb, const float* __restrict__ context,
    const float* __restrict__ h0, const float* __restrict__ c0,
    const float* __restrict__ coverage,
    const float* __restrict__ PM, const float* __restrict__ d1,
    const float* __restrict__ d2,
    float* __restrict__ A1, float* __restrict__ c_cur,
    float* __restrict__ out, int t)
{
  __shared__ float ueh[8][644];   // [emb(128) | h(512)]
  __shared__ float uc[8][516];    // t==0: context(512) ; t>=1: probs(400)
  __shared__ float part[256];
  __shared__ float gl[64];
  __shared__ float invs[8];
  int tid = threadIdx.x, blk = blockIdx.x;

  if (t >= 1 && tid < 8)
    invs[tid] = 1.0f / (d2[(t-1)*8 + tid] + 1e-12f*d1[(t-1)*8 + tid]);
  __syncthreads();

  // stage ueh: 1280 float4 slots (8 b x (32 emb + 128 h))
  for (int i = 0; i < 5; ++i) {
    int slot = i*256 + tid;
    int b = slot / 160, sl = slot - b*160;
    if (sl < 32) {
      *(float4*)&ueh[b][sl*4] = *(const float4*)(emb + (size_t)(b*16+t)*128 + sl*4);
    } else {
      int qq = sl - 32;
      const float* hsrc = t ? (A1 + ((size_t)((t-1)*8+b))*1024) : (h0 + b*512);
      *(float4*)&ueh[b][128 + qq*4] = *(const float4*)(hsrc + qq*4);
    }
  }
  if (t == 0) {
    for (int i = 0; i < 4; ++i) {
      int slot = i*256 + tid;
      int b = slot >> 7, sl = slot & 127;
      *(float4*)&uc[b][sl*4] = *(const float4*)(context + b*512 + sl*4);
    }
  } else {
    const float* pmsrc = PM + (size_t)(t-1)*3200;
    for (int i = 0; i < 4; ++i) {
      int slot = i*256 + tid;
      if (slot < 800) {
        int b = slot / 100, sl = slot - b*100;
        float4 p4 = *(const float4*)(pmsrc + b*400 + sl*4);
        float iv = invs[b];
        p4.x *= iv; p4.y *= iv; p4.z *= iv; p4.w *= iv;
        *(float4*)&uc[b][sl*4] = p4;
      }
    }
  }
  __syncthreads();

  // blk<8 & t>=1: write out4/out6 for (b=blk, t-1)
  if (t >= 1 && blk < 8) {
    int b = blk;
    const float* covprev = (t == 1) ? (coverage + b*400)
                                    : (out + O6 + ((size_t)(b*16 + t-2))*400);
    size_t o = ((size_t)(b*16 + t-1))*400;
    for (int s = tid; s < 400; s += 256) {
      float pr = uc[b][s];
      out[O4 + o + s] = pr;
      out[O6 + o + s] = covprev[s] + pr;
    }
  }

  int dot = tid >> 2, kq = tid & 3;
  int rr = dot >> 3, b = dot & 7;
  int gate = rr >> 1, jj = rr & 1;
  int r = gate*512 + blk*2 + jj;
  const unsigned short* gr = G + (size_t)r*1152;
  float acc = 0.f;
  // emb part (128)
  {
    const unsigned short* gp = gr + kq*8;
    const float* up = &ueh[b][kq*8];
#pragma unroll
    for (int i = 0; i < 4; ++i) {
      ushort8_t w8 = *(const ushort8_t*)(gp + i*32);
      float4 u0 = *(const float4*)(up + i*32);
      float4 u1 = *(const float4*)(up + i*32 + 4);
      acc += bfu(w8[0])*u0.x + bfu(w8[1])*u0.y + bfu(w8[2])*u0.z + bfu(w8[3])*u0.w
           + bfu(w8[4])*u1.x + bfu(w8[5])*u1.y + bfu(w8[6])*u1.z + bfu(w8[7])*u1.w;
    }
  }
  // h part (512)
  {
    const unsigned short* gp = gr + 640 + kq*8;
    const float* up = &ueh[b][128 + kq*8];
#pragma unroll 4
    for (int i = 0; i < 16; ++i) {
      ushort8_t w8 = *(const ushort8_t*)(gp + i*32);
      float4 u0 = *(const float4*)(up + i*32);
      float4 u1 = *(const float4*)(up + i*32 + 4);
      acc += bfu(w8[0])*u0.x + bfu(w8[1])*u0.y + bfu(w8[2])*u0.z + bfu(w8[3])*u0.w
           + bfu(w8[4])*u1.x + bfu(w8[5])*u1.y + bfu(w8[6])*u1.z + bfu(w8[7])*u1.w;
    }
  }
  if (t == 0) {
    // ctx part via G cols 128..639
    const unsigned short* gp = gr + 128 + kq*8;
    const float* up = &uc[b][kq*8];
#pragma unroll 4
    for (int i = 0; i < 16; ++i) {
      ushort8_t w8 = *(const ushort8_t*)(gp + i*32);
      float4 u0 = *(const float4*)(up + i*32);
      float4 u1 = *(const float4*)(up + i*32 + 4);
      acc += bfu(w8[0])*u0.x + bfu(w8[1])*u0.y + bfu(w8[2])*u0.z + bfu(w8[3])*u0.w
           + bfu(w8[4])*u1.x + bfu(w8[5])*u1.y + bfu(w8[6])*u1.z + bfu(w8[7])*u1.w;
    }
  } else {
    // ctx part via probs . encG[b, r, :]
    const unsigned short* gp = encG + ((size_t)(b*2048 + r))*400 + kq*8;
    const float* up = &uc[b][kq*8];
#pragma unroll 4
    for (int i = 0; i < 12; ++i) {
      ushort8_t w8 = *(const ushort8_t*)(gp + i*32);
      float4 u0 = *(const float4*)(up + i*32);
      float4 u1 = *(const float4*)(up + i*32 + 4);
      acc += bfu(w8[0])*u0.x + bfu(w8[1])*u0.y + bfu(w8[2])*u0.z + bfu(w8[3])*u0.w
           + bfu(w8[4])*u1.x + bfu(w8[5])*u1.y + bfu(w8[6])*u1.z + bfu(w8[7])*u1.w;
    }
    if (kq < 2) {
      ushort8_t w8 = *(const ushort8_t*)(gp + 12*32);
      float4 u0 = *(const float4*)(up + 12*32);
      float4 u1 = *(const float4*)(up + 12*32 + 4);
      acc += bfu(w8[0])*u0.x + bfu(w8[1])*u0.y + bfu(w8[2])*u0.z + bfu(w8[3])*u0.w
           + bfu(w8[4])*u1.x + bfu(w8[5])*u1.y + bfu(w8[6])*u1.z + bfu(w8[7])*u1.w;
    }
  }
  part[tid] = acc;
  __syncthreads();
  if (tid < 64) {
    int rr2 = tid >> 3;
    int r2 = (rr2 >> 1)*512 + blk*2 + (rr2 & 1);
    gl[tid] = part[tid*4] + part[tid*4+1] + part[tid*4+2] + part[tid*4+3] + gb[r2];
  }
  __syncthreads();
  if (tid < 16) {
    int jj2 = tid >> 3, b2 = tid & 7;
    float gi = gl[(0*2+jj2)*8 + b2];
    float gf = gl[(1*2+jj2)*8 + b2];
    float gg = gl[(2*2+jj2)*8 + b2];
    float go = gl[(3*2+jj2)*8 + b2];
    int j = blk*2 + jj2;
    float cp = t ? c_cur[b2*512+j] : c0[b2*512+j];
    float cn = sigm(gf)*cp + sigm(gi)*ftanh(gg);
    float hn = sigm(go)*ftanh(cn);
    c_cur[b2*512+j] = cn;
    A1[((size_t)(t*8+b2))*1024 + j] = hn;
  }
}

// S2: hp[b,p] = eb[p] + ewh@h(t) ; 64 blocks x 256 thr
__global__ __launch_bounds__(256) void s2_hp(
    const unsigned short* __restrict__ ewhb, const float* __restrict__ eb,
    const float* __restrict__ A1, float* __restrict__ hp, int t)
{
  __shared__ float hl[8*516];
  __shared__ float part[256];
  int tid = threadIdx.x, pc = blockIdx.x;
  for (int b = 0; b < 8; ++b)
    for (int k = tid; k < 512; k += 256)
      hl[b*516 + k] = A1[((size_t)(t*8+b))*1024 + k];
  __syncthreads();
  int dot = tid >> 2, kq = tid & 3;
  int rr = dot >> 3, b = dot & 7;
  int p = pc*8 + rr;
  const unsigned short* wp = ewhb + (size_t)p*512 + kq*16;
  const float* hh = hl + b*516 + kq*16;
  float acc = 0.f;
#pragma unroll
  for (int i = 0; i < 8; ++i) {
    ushort8_t wa = *(const ushort8_t*)(wp + i*64);
    ushort8_t wb = *(const ushort8_t*)(wp + i*64 + 8);
    float4 h0v = *(const float4*)(hh + i*64);
    float4 h1v = *(const float4*)(hh + i*64 + 4);
    float4 h2v = *(const float4*)(hh + i*64 + 8);
    float4 h3v = *(const float4*)(hh + i*64 + 12);
    acc += bfu(wa[0])*h0v.x + bfu(wa[1])*h0v.y + bfu(wa[2])*h0v.z + bfu(wa[3])*h0v.w
         + bfu(wa[4])*h1v.x + bfu(wa[5])*h1v.y + bfu(wa[6])*h1v.z + bfu(wa[7])*h1v.w
         + bfu(wb[0])*h2v.x + bfu(wb[1])*h2v.y + bfu(wb[2])*h2v.z + bfu(wb[3])*h2v.w
         + bfu(wb[4])*h3v.x + bfu(wb[5])*h3v.y + bfu(wb[6])*h3v.z + bfu(wb[7])*h3v.w;
  }
  part[tid] = acc;
  __syncthreads();
  if (tid < 64) {
    int rr2 = tid >> 3, b2 = tid & 7;
    int p2 = pc*8 + rr2;
    hp[b2*512 + p2] = eb[p2] + part[tid*4] + part[tid*4+1] + part[tid*4+2] + part[tid*4+3];
  }
}

// S3: pm[b,s] = exp(e[b,s])*mask ; atomic D1/D2 sums. 128 blocks (8b x 16sc)
__global__ __launch_bounds__(256) void s3e(
    const unsigned short* __restrict__ encpb, const float* __restrict__ hp,
    const float* __restrict__ vvec, const float* __restrict__ covw,
    const float* __restrict__ masks, const float* __restrict__ coverage,
    const float* __restrict__ out6v, float* __restrict__ PM,
    float* __restrict__ d1, float* __restrict__ d2, int t)
{
  int tid = threadIdx.x;
  int b = blockIdx.x >> 4, sc = blockIdx.x & 15;
  int w = tid >> 6, lane = tid & 63;
  int h0i = lane*8;
  __shared__ float red1[4], red2[4];
  float hpv[8], vv[8], cw[8];
  {
    const float* hpp = hp + b*512 + h0i;
    float4 a0 = *(const float4*)(hpp), a1 = *(const float4*)(hpp+4);
    hpv[0]=a0.x; hpv[1]=a0.y; hpv[2]=a0.z; hpv[3]=a0.w;
    hpv[4]=a1.x; hpv[5]=a1.y; hpv[6]=a1.z; hpv[7]=a1.w;
    float4 v0 = *(const float4*)(vvec+h0i), v1 = *(const float4*)(vvec+h0i+4);
    vv[0]=v0.x; vv[1]=v0.y; vv[2]=v0.z; vv[3]=v0.w;
    vv[4]=v1.x; vv[5]=v1.y; vv[6]=v1.z; vv[7]=v1.w;
    float4 c0v = *(const float4*)(covw+h0i), c1v = *(const float4*)(covw+h0i+4);
    cw[0]=c0v.x; cw[1]=c0v.y; cw[2]=c0v.z; cw[3]=c0v.w;
    cw[4]=c1v.x; cw[5]=c1v.y; cw[6]=c1v.z; cw[7]=c1v.w;
  }
  const float* covp = t ? (out6v + ((size_t)(b*16 + t-1))*400) : (coverage + b*400);
  float a1s = 0.f, a2s = 0.f;
  for (int sl = w; sl < 25; sl += 4) {
    int s = sc*25 + sl;
    float cv = covp[s];
    const unsigned short* ep = encpb + ((size_t)(b*400+s))*512 + h0i;
    ushort8_t e8 = *(const ushort8_t*)ep;
    float acc = 0.f;
#pragma unroll
    for (int i = 0; i < 8; ++i)
      acc += ftanh(hpv[i] + bfu(e8[i]) + cv*cw[i]) * vv[i];
    for (int off = 32; off > 0; off >>= 1) acc += __shfl_down(acc, off);
    if (lane == 0) {
      float pe = __expf(acc);
      float pmv = pe * masks[b*400 + s];
      PM[(size_t)t*3200 + b*400 + s] = pmv;
      a1s += pe; a2s += pmv;
    }
  }
  if (lane == 0) { red1[w] = a1s; red2[w] = a2s; }
  __syncthreads();
  if (tid == 0) {
    atomicAdd(&d1[t*8+b], red1[0]+red1[1]+red1[2]+red1[3]);
    atomicAdd(&d2[t*8+b], red2[0]+red2[1]+red2[2]+red2[3]);
  }
}

// ctx for ALL t (post-loop): A1 ctx cols; also out4/out6 for t=15.
// 32 blocks (b = blk>>2, cc = blk&3), 256 thr.
__global__ __launch_bounds__(256) void ctx_all(
    const float* __restrict__ PM, const float* __restrict__ d1,
    const float* __restrict__ d2, const float* __restrict__ enc,
    float* __restrict__ A1, float* __restrict__ out)
{
  int tid = threadIdx.x;
  int b = blockIdx.x >> 2, cc = blockIdx.x & 3;
  __shared__ float prl[16][400];
  __shared__ float redbuf[16][128];
  __shared__ float invs[16];
  if (tid < 16) invs[tid] = 1.0f / (d2[tid*8+b] + 1e-12f*d1[tid*8+b]);
  __syncthreads();
  for (int i = 0; i < 7; ++i) {
    int slot = i*256 + tid;
    if (slot < 1600) {
      int tt = slot / 100, sl = slot - tt*100;
      float4 p4 = *(const float4*)(PM + (size_t)tt*3200 + b*400 + sl*4);
      float iv = invs[tt];
      p4.x *= iv; p4.y *= iv; p4.z *= iv; p4.w *= iv;
      *(float4*)&prl[tt][sl*4] = p4;
    }
  }
  __syncthreads();
  if (cc == 0) {
    size_t o15 = ((size_t)(b*16 + 15))*400;
    size_t o14 = ((size_t)(b*16 + 14))*400;
    for (int s = tid; s < 400; s += 256) {
      float pr = prl[15][s];
      out[O4 + o15 + s] = pr;
      out[O6 + o15 + s] = out[O6 + o14 + s] + pr;
    }
  }
  int c = cc*128 + (tid & 127);
  int sg = tid >> 7;
  float acc[16];
#pragma unroll
  for (int tt = 0; tt < 16; ++tt) acc[tt] = 0.f;
  for (int s = sg*200; s < sg*200 + 200; ++s) {
    float ev = enc[((size_t)(b*400 + s))*512 + c];
#pragma unroll
    for (int tt = 0; tt < 16; ++tt) acc[tt] += prl[tt][s]*ev;
  }
  if (sg == 1) {
#pragma unroll
    for (int tt = 0; tt < 16; ++tt) redbuf[tt][tid & 127] = acc[tt];
  }
  __syncthreads();
  if (sg == 0) {
#pragma unroll
    for (int tt = 0; tt < 16; ++tt)
      A1[((size_t)(tt*8+b))*1024 + 512 + c] = acc[tt] + redbuf[tt][tid & 127];
  }
}

// Epilogue: pgen all (t,b) + out1/2/3/5 + rowsum zero
__global__ __launch_bounds__(256) void e_pgen(
    const float* __restrict__ A1, const float* __restrict__ c_cur,
    const float* __restrict__ emb, const float* __restrict__ context,
    const float* __restrict__ pw, const float* __restrict__ q,
    const float* __restrict__ qb, float* __restrict__ pgen,
    float* __restrict__ rowsum, float* __restrict__ out)
{
  int blk = blockIdx.x, tid = threadIdx.x;
  if (blk < 128) {
    int m = blk, t = m >> 3, b = m & 7;
    const float* ctxT = A1 + (size_t)m*1024 + 512;
    const float* hT   = A1 + (size_t)m*1024;
    const float* embp = emb + (size_t)(b*16+t)*128;
    const float* ctxP = t ? (A1 + ((size_t)((t-1)*8+b))*1024 + 512) : (context + b*512);
    float acc = 0.f;
    for (int k = tid; k < 512; k += 256)
      acc += pw[k]*ctxT[k] + pw[512+k]*hT[k] + q[128+k]*ctxP[k];
    if (tid < 128) acc += q[tid]*embp[tid];
    for (int off = 32; off > 0; off >>= 1) acc += __shfl_down(acc, off);
    __shared__ float red[4];
    if (!(tid & 63)) red[tid>>6] = acc;
    __syncthreads();
    if (tid == 0) {
      float pg = sigm(red[0]+red[1]+red[2]+red[3] + qb[0]);
      pgen[m] = pg;
      if (t == 15) out[O5 + b] = pg;
    }
  } else if (blk == 128) {
    for (int i = tid; i < 4096; i += 256) {
      int b = i >> 9, j = i & 511;
      out[O1 + i] = A1[((size_t)(120+b))*1024 + 512 + j];
    }
  } else if (blk == 129) {
    for (int i = tid; i < 4096; i += 256) {
      int b = i >> 9, j = i & 511;
      out[O2 + i] = A1[((size_t)(120+b))*1024 + j];
    }
  } else if (blk == 130) {
    for (int i = tid; i < 4096; i += 256) out[O3 + i] = c_cur[i];
  } else {
    if (tid < 128) rowsum[tid] = 0.f;
  }
}

// scale by pg/rowsum + OOV cols
__global__ __launch_bounds__(256) void k_scale(
    float* __restrict__ out, const float* __restrict__ pgen,
    const float* __restrict__ rowsum, const float* __restrict__ ez)
{
  int orow = blockIdx.x, cy = blockIdx.y, tid = threadIdx.x;
  int b = orow >> 4, t = orow & 15;
  float sc = pgen[t*8+b] / rowsum[orow];
  int c0 = cy*6256;
  int c1 = (cy == 7) ? VE : c0 + 6256;
  float* row = out + (size_t)orow*VE;
  for (int c = c0 + tid*4; c < c1; c += 1024) {
    if (c + 4 <= VV && c + 4 <= c1) {
      float4 v = *(float4*)(row + c);
      v.x *= sc; v.y *= sc; v.z *= sc; v.w *= sc;
      *(float4*)(row + c) = v;
    } else {
      for (int e = 0; e < 4; ++e) {
        int cc2 = c + e;
        if (cc2 < c1) row[cc2] = (cc2 < VV) ? row[cc2]*sc : ez[b*OOVn + cc2 - VV];
      }
    }
  }
}

// copy-mechanism scatter
__global__ __launch_bounds__(256) void k_scatter(
    float* __restrict__ out, const float* __restrict__ pgen,
    const int* __restrict__ extidx)
{
  int m = blockIdx.x, tid = threadIdx.x;  // m = t*8+b
  int b = m & 7, t = m >> 3;
  float* row = out + ((size_t)(b*TT + t))*VE;
  float onem = 1.0f - pgen[m];
  const float* pr = out + O4 + ((size_t)(b*TT+t))*SS;
  for (int s = tid; s < SS; s += 256) {
    int ix = extidx[b*SS + s];
    atomicAdd(&row[ix], onem * pr[s]);
  }
}

extern "C" void kernel_launch(void* const* d_in, const int* in_sizes, int n_in,
                              void* d_out, int out_size, void* d_ws, size_t ws_size,
                              hipStream_t stream)
{
  (void)in_sizes; (void)n_in; (void)out_size; (void)ws_size;
  const float* emb      = (const float*)d_in[0];
  const float* context  = (const float*)d_in[1];
  const float* h0       = (const float*)d_in[2];
  const float* c0       = (const float*)d_in[3];
  const float* enc      = (const float*)d_in[4];
  const float* masks    = (const float*)d_in[5];
  const float* ez       = (const float*)d_in[6];
  const int*   extidx   = (const int*)d_in[7];
  const float* coverage = (const float*)d_in[8];
  const float* wih      = (const float*)d_in[9];
  const float* whh      = (const float*)d_in[10];
  const float* bih      = (const float*)d_in[11];
  const float* bhh      = (const float*)d_in[12];
  const float* covw     = (const float*)d_in[13];
  const float* ew       = (const float*)d_in[14];
  const float* eb       = (const float*)d_in[15];
  const float* vvec     = (const float*)d_in[16];
  const float* xw       = (const float*)d_in[17];
  const float* xb       = (const float*)d_in[18];
  const float* aw       = (const float*)d_in[19];
  const float* ab       = (const float*)d_in[20];
  const float* vw       = (const float*)d_in[21];
  const float* vb       = (const float*)d_in[22];
  const float* pw       = (const float*)d_in[23];
  const float* pb       = (const float*)d_in[24];
  float* out = (float*)d_out;

  float* ws = (float*)d_ws;
  float* A1       = ws;                 // 128 x 1024 [h | ctx]
  float* c_cur    = ws + 131072;        // 4096
  float* hp       = ws + 135168;        // 4096
  unsigned short* attnd_bf = (unsigned short*)(ws + 139264);  // 128x512
  float* pgen     = ws + 172032;        // 128
  float* gb       = ws + 172160;        // 2048
  float* q        = ws + 174208;        // 640
  float* qb       = ws + 174848;        // 1
  float* d1       = ws + 174852;        // 128
  float* d2       = ws + 174980;        // 128
  float* rowsum   = ws + 175108;        // 128

  unsigned short* G     = (unsigned short*)(out + G_OFF);
  unsigned short* ewhb  = (unsigned short*)(out + EWHB_OFF);
  unsigned short* encG  = (unsigned short*)(out + ENCG_OFF);
  float*          wxf   = out + WXF_OFF;
  unsigned short* encpb = (unsigned short*)(out + ENCP_OFF);
  float*          PM    = out + PM_OFF;

  // Prologue
  p_wx<<<1152, 256, 0, stream>>>(wih, whh, xw, G, wxf);
  p_small<<<12, 256, 0, stream>>>(wih, bih, bhh, xb, xw, pw, pb, gb, q, qb, d1, d2);
  p_cast<<<128, 256, 0, stream>>>(ew, ewhb);
  // encG[b] = Wx_ctx @ enc_b^T  (bf16 out, batched over b)
  gemm_bt<<<dim3(16,7,8), 256, 0, stream>>>(wxf, 512, enc, 512,
      (const float*)nullptr, (float*)encG, 400, 400, 512, 0, 1,
      (long)400*512, (long)2048*400);
  // encp = enc @ energy_w[:,512:].T  (bf16 out; overwrites wxf region - ok)
  gemm_bt<<<dim3(25,8,1), 256, 0, stream>>>(enc, 512, ew + 512, 1024,
      (const float*)nullptr, (float*)encpb, 512, 512, 512, 0, 1, 0, 0);

  for (int t = 0; t < TT; ++t) {
    s1g<<<256, 256, 0, stream>>>(G, encG, gb, emb, context, h0, c0, coverage,
                                 PM, d1, d2, A1, c_cur, out, t);
    s2_hp<<<64, 256, 0, stream>>>(ewhb, eb, A1, hp, t);
    s3e<<<128, 256, 0, stream>>>(encpb, hp, vvec, covw, masks, coverage,
                                 out + O6, PM, d1, d2, t);
  }

  ctx_all<<<32, 256, 0, stream>>>(PM, d1, d2, enc, A1, out);
  e_pgen<<<132, 256, 0, stream>>>(A1, c_cur, emb, context, pw, q, qb, pgen, rowsum, out);
  // attnd_bf = bf16([h|ctx] @ attnd_w.T + attnd_b)
  gemm_bt<<<dim3(1,8,1), 256, 0, stream>>>(A1, 1024, aw, 1024, ab,
      (float*)attnd_bf, 512, 512, 1024, 0, 1, 0, 0);
  // logits: exp(attnd_bf @ vocab_w.T + vb) -> out rows (b*16+t), + rowsums
  gemm_logits<<<782, 256, 0, stream>>>(attnd_bf, vw, vb, out, rowsum);
  k_scale<<<dim3(128,8), 256, 0, stream>>>(out, pgen, rowsum, ez);
  k_scatter<<<128, 256, 0, stream>>>(out, pgen, extidx);
}